// Round 7
// baseline (403.984 us; speedup 1.0000x reference)
//
#include <hip/hip_runtime.h>
#include <hip/hip_bf16.h>

typedef __bf16 bf16_t;
typedef __bf16 bf16x8 __attribute__((ext_vector_type(8)));
typedef __bf16 bf16x4 __attribute__((ext_vector_type(4)));
typedef float floatx4 __attribute__((ext_vector_type(4)));
typedef float floatx16 __attribute__((ext_vector_type(16)));

#define S_LEN 2048
#define D_DIM 2048
#define NHEADS 32
#define DH 64

// async global->LDS, 16B per lane; LDS dest = wave-uniform base + lane*16
__device__ __forceinline__ void gll16(const bf16_t* g, bf16_t* l) {
    __builtin_amdgcn_global_load_lds(
        (const __attribute__((address_space(1))) unsigned int*)g,
        (__attribute__((address_space(3))) unsigned int*)l, 16, 0, 0);
}

#define BAR()    asm volatile("s_barrier" ::: "memory")
#define WAIT(N)  asm volatile("s_waitcnt vmcnt(" #N ")" ::: "memory")
#define DSWAIT() asm volatile("s_waitcnt lgkmcnt(0)" ::: "memory")

// ---------------- prep: z=0..3 weight transpose+cvt, z=4 hidden-state cvt ----------------
__global__ __launch_bounds__(256) void k_prep(
    const float* __restrict__ hs, bf16_t* __restrict__ Xb,
    const float* __restrict__ W0, const float* __restrict__ W1,
    const float* __restrict__ W2, const float* __restrict__ W3,
    bf16_t* __restrict__ T0, bf16_t* __restrict__ T1,
    bf16_t* __restrict__ T2, bf16_t* __restrict__ T3)
{
    const int t = threadIdx.x;
    if (blockIdx.z == 4) {
        const int bid = blockIdx.y * 32 + blockIdx.x;
        const int i = (bid * 256 + t) * 16;
        const float4 a0 = *(const float4*)(hs + i);
        const float4 a1 = *(const float4*)(hs + i + 4);
        const float4 a2 = *(const float4*)(hs + i + 8);
        const float4 a3 = *(const float4*)(hs + i + 12);
        bf16x8 o0, o1;
        o0[0]=(bf16_t)a0.x; o0[1]=(bf16_t)a0.y; o0[2]=(bf16_t)a0.z; o0[3]=(bf16_t)a0.w;
        o0[4]=(bf16_t)a1.x; o0[5]=(bf16_t)a1.y; o0[6]=(bf16_t)a1.z; o0[7]=(bf16_t)a1.w;
        o1[0]=(bf16_t)a2.x; o1[1]=(bf16_t)a2.y; o1[2]=(bf16_t)a2.z; o1[3]=(bf16_t)a2.w;
        o1[4]=(bf16_t)a3.x; o1[5]=(bf16_t)a3.y; o1[6]=(bf16_t)a3.z; o1[7]=(bf16_t)a3.w;
        *(bf16x8*)(Xb + i) = o0;
        *(bf16x8*)(Xb + i + 8) = o1;
        return;
    }
    const float* W; bf16_t* T;
    switch (blockIdx.z) {
        case 0: W = W0; T = T0; break;
        case 1: W = W1; T = T1; break;
        case 2: W = W2; T = T2; break;
        default: W = W3; T = T3; break;
    }
    __shared__ float tile_t[64][68];
    const int n0 = blockIdx.x * 64, k0 = blockIdx.y * 64;
    #pragma unroll
    for (int i = 0; i < 16; ++i) {
        const int r = i * 4 + (t >> 6);
        const int c = t & 63;
        tile_t[c][r] = W[(size_t)(k0 + r) * D_DIM + n0 + c];
    }
    __syncthreads();
    #pragma unroll
    for (int j = 0; j < 4; ++j) {
        const int n  = j * 16 + (t >> 4);
        const int k4 = (t & 15) * 4;
        const float4 v = *(const float4*)&tile_t[n][k4];
        bf16x4 pk;
        pk[0] = (bf16_t)v.x; pk[1] = (bf16_t)v.y; pk[2] = (bf16_t)v.z; pk[3] = (bf16_t)v.w;
        *(bf16x4*)(T + (size_t)(n0 + n) * D_DIM + k0 + k4) = pk;
    }
}

// ================= GEMM =================
#define BM 128
#define BN 128
#define BK 32

// QKV GEMM: 2-deep async pipeline, triple-buffered LDS, raw barriers.
__global__ __launch_bounds__(256) void k_gemm_qkv(
    const bf16_t* __restrict__ A,
    const bf16_t* __restrict__ Bt0, const bf16_t* __restrict__ Bt1, const bf16_t* __restrict__ Bt2,
    const float* __restrict__ bias0, const float* __restrict__ bias1, const float* __restrict__ bias2,
    bf16_t* __restrict__ Qout, bf16_t* __restrict__ Kout, bf16_t* __restrict__ VtOut,
    int M, int N, int K)
{
    const bf16_t* Bt; const float* bias;
    if (blockIdx.z == 0)      { Bt = Bt0; bias = bias0; }
    else if (blockIdx.z == 1) { Bt = Bt1; bias = bias1; }
    else                      { Bt = Bt2; bias = bias2; }

    __shared__ bf16_t As[3][BM][BK];
    __shared__ bf16_t Bs[3][BN][BK];

    const int t    = threadIdx.x;
    const int lane = t & 63;
    const int wave = t >> 6;
    const int wm = (wave >> 1) * 64;
    const int wn = (wave & 1) * 64;
    const int bm = blockIdx.y * BM;
    const int bn = blockIdx.x * BN;
    const int lm = lane & 15;
    const int lq = lane >> 4;

    const int srow0 = wave * 32 + (lane >> 2);
    const int srow1 = srow0 + 16;
    const int cp    = lane & 3;
    const int gc0 = cp ^ ((srow0 >> 1) & 3);
    const int gc1 = cp ^ ((srow1 >> 1) & 3);

    const bf16_t* Ag0 = A  + (size_t)(bm + srow0) * K + gc0 * 8;
    const bf16_t* Ag1 = A  + (size_t)(bm + srow1) * K + gc1 * 8;
    const bf16_t* Bg0 = Bt + (size_t)(bn + srow0) * K + gc0 * 8;
    const bf16_t* Bg1 = Bt + (size_t)(bn + srow1) * K + gc1 * 8;

    floatx4 acc[4][4];
    #pragma unroll
    for (int i = 0; i < 4; ++i)
        #pragma unroll
        for (int j = 0; j < 4; ++j)
            #pragma unroll
            for (int r = 0; r < 4; ++r) acc[i][j][r] = 0.f;

    const int NIT = K / BK;
    auto stage = [&](int buf, int k0) {
        gll16(Ag0 + k0, &As[buf][wave * 32][0]);
        gll16(Ag1 + k0, &As[buf][wave * 32 + 16][0]);
        gll16(Bg0 + k0, &Bs[buf][wave * 32][0]);
        gll16(Bg1 + k0, &Bs[buf][wave * 32 + 16][0]);
    };
    stage(0, 0);
    stage(1, BK);

    for (int i = 0; i < NIT; ++i) {
        BAR();
        if (i + 2 < NIT) {
            stage((i + 2) % 3, (i + 2) * BK);
            WAIT(8);
        } else if (i + 1 < NIT) {
            WAIT(4);
        } else {
            WAIT(0);
        }
        BAR();

        const int buf = i % 3;
        bf16x8 af[4], bfr[4];
        #pragma unroll
        for (int ii = 0; ii < 4; ++ii) {
            const int row = wm + ii * 16 + lm;
            af[ii] = *(const bf16x8*)&As[buf][row][(lq ^ ((row >> 1) & 3)) * 8];
        }
        #pragma unroll
        for (int j = 0; j < 4; ++j) {
            const int row = wn + j * 16 + lm;
            bfr[j] = *(const bf16x8*)&Bs[buf][row][(lq ^ ((row >> 1) & 3)) * 8];
        }
        #pragma unroll
        for (int ii = 0; ii < 4; ++ii)
            #pragma unroll
            for (int j = 0; j < 4; ++j)
                acc[ii][j] = __builtin_amdgcn_mfma_f32_16x16x32_bf16(af[ii], bfr[j], acc[ii][j], 0, 0, 0);
    }

    if (blockIdx.z == 2) {
        #pragma unroll
        for (int i = 0; i < 4; ++i) {
            const int row0 = bm + wm + i * 16 + lq * 4;
            #pragma unroll
            for (int j = 0; j < 4; ++j) {
                const int col = bn + wn + j * 16 + lm;
                const float bb = bias[col];
                bf16x4 pk;
                #pragma unroll
                for (int r = 0; r < 4; ++r) pk[r] = (bf16_t)(acc[i][j][r] + bb);
                *(bf16x4*)(VtOut + (size_t)col * M + row0) = pk;
            }
        }
    } else {
        bf16_t* C = (blockIdx.z == 0) ? Qout : Kout;
        #pragma unroll
        for (int i = 0; i < 4; ++i) {
            const int row0 = bm + wm + i * 16 + lq * 4;
            #pragma unroll
            for (int j = 0; j < 4; ++j) {
                const int col = bn + wn + j * 16 + lm;
                const float bb = bias[col];
                #pragma unroll
                for (int r = 0; r < 4; ++r)
                    C[(size_t)(row0 + r) * N + col] = (bf16_t)(acc[i][j][r] + bb);
            }
        }
    }
}

// Split-K GEMM (O-projection): z in {0,1,2} covers a K-slice, writes f32 partials.
__global__ __launch_bounds__(256) void k_gemm_splitk(
    const bf16_t* __restrict__ A, const bf16_t* __restrict__ Bt,
    float* __restrict__ P0, float* __restrict__ P1, float* __restrict__ P2,
    int M, int N, int K)
{
    __shared__ bf16_t As[3][BM][BK];
    __shared__ bf16_t Bs[3][BN][BK];

    const int t    = threadIdx.x;
    const int lane = t & 63;
    const int wave = t >> 6;
    const int wm = (wave >> 1) * 64;
    const int wn = (wave & 1) * 64;
    const int bm = blockIdx.y * BM;
    const int bn = blockIdx.x * BN;
    const int lm = lane & 15;
    const int lq = lane >> 4;
    const int z  = blockIdx.z;

    const int nit_all = K / BK;
    const int it0 = (z * nit_all) / 3;
    const int it1 = ((z + 1) * nit_all) / 3;
    const int NIT = it1 - it0;
    const int kbase = it0 * BK;

    const int srow0 = wave * 32 + (lane >> 2);
    const int srow1 = srow0 + 16;
    const int cp    = lane & 3;
    const int gc0 = cp ^ ((srow0 >> 1) & 3);
    const int gc1 = cp ^ ((srow1 >> 1) & 3);

    const bf16_t* Ag0 = A  + (size_t)(bm + srow0) * K + kbase + gc0 * 8;
    const bf16_t* Ag1 = A  + (size_t)(bm + srow1) * K + kbase + gc1 * 8;
    const bf16_t* Bg0 = Bt + (size_t)(bn + srow0) * K + kbase + gc0 * 8;
    const bf16_t* Bg1 = Bt + (size_t)(bn + srow1) * K + kbase + gc1 * 8;

    floatx4 acc[4][4];
    #pragma unroll
    for (int i = 0; i < 4; ++i)
        #pragma unroll
        for (int j = 0; j < 4; ++j)
            #pragma unroll
            for (int r = 0; r < 4; ++r) acc[i][j][r] = 0.f;

    auto stage = [&](int buf, int k0) {
        gll16(Ag0 + k0, &As[buf][wave * 32][0]);
        gll16(Ag1 + k0, &As[buf][wave * 32 + 16][0]);
        gll16(Bg0 + k0, &Bs[buf][wave * 32][0]);
        gll16(Bg1 + k0, &Bs[buf][wave * 32 + 16][0]);
    };
    stage(0, 0);
    if (1 < NIT) stage(1, BK);

    for (int i = 0; i < NIT; ++i) {
        BAR();
        if (i + 2 < NIT) {
            stage((i + 2) % 3, (i + 2) * BK);
            WAIT(8);
        } else if (i + 1 < NIT) {
            WAIT(4);
        } else {
            WAIT(0);
        }
        BAR();

        const int buf = i % 3;
        bf16x8 af[4], bfr[4];
        #pragma unroll
        for (int ii = 0; ii < 4; ++ii) {
            const int row = wm + ii * 16 + lm;
            af[ii] = *(const bf16x8*)&As[buf][row][(lq ^ ((row >> 1) & 3)) * 8];
        }
        #pragma unroll
        for (int j = 0; j < 4; ++j) {
            const int row = wn + j * 16 + lm;
            bfr[j] = *(const bf16x8*)&Bs[buf][row][(lq ^ ((row >> 1) & 3)) * 8];
        }
        #pragma unroll
        for (int ii = 0; ii < 4; ++ii)
            #pragma unroll
            for (int j = 0; j < 4; ++j)
                acc[ii][j] = __builtin_amdgcn_mfma_f32_16x16x32_bf16(af[ii], bfr[j], acc[ii][j], 0, 0, 0);
    }

    float* C = (z == 0) ? P0 : (z == 1) ? P1 : P2;
    #pragma unroll
    for (int i = 0; i < 4; ++i) {
        const int row0 = bm + wm + i * 16 + lq * 4;
        #pragma unroll
        for (int j = 0; j < 4; ++j) {
            const int col = bn + wn + j * 16 + lm;
            #pragma unroll
            for (int r = 0; r < 4; ++r)
                C[(size_t)(row0 + r) * N + col] = acc[i][j][r];
        }
    }
}

// out = bias + p0 + p1 + p2
__global__ __launch_bounds__(256) void k_reduce_bias(
    const float* __restrict__ P0, const float* __restrict__ P1,
    const float* __restrict__ P2, const float* __restrict__ bias,
    float* __restrict__ out)
{
    const int i = (blockIdx.x * 256 + threadIdx.x) * 4;
    const float4 b  = *(const float4*)(bias + (i & (D_DIM - 1)));
    const float4 a0 = *(const float4*)(P0 + i);
    const float4 a1 = *(const float4*)(P1 + i);
    const float4 a2 = *(const float4*)(P2 + i);
    float4 o;
    o.x = b.x + a0.x + a1.x + a2.x;
    o.y = b.y + a0.y + a1.y + a2.y;
    o.z = b.z + a0.z + a1.z + a2.z;
    o.w = b.w + a0.w + a1.w + a2.w;
    *(float4*)(out + i) = o;
}

// ---------------- RMSNorm (full D) + interleaved RoPE, bf16 in-place ----------------
__global__ __launch_bounds__(256) void k_norm_rope(
    bf16_t* __restrict__ Q, bf16_t* __restrict__ Kb_,
    const float* __restrict__ qw, const float* __restrict__ kw,
    const float* __restrict__ cosb, const float* __restrict__ sinb)
{
    bf16_t* X = (blockIdx.z == 0) ? Q : Kb_;
    const float* w = (blockIdx.z == 0) ? qw : kw;
    const int row = blockIdx.x;
    const int t = threadIdx.x;
    const size_t base = (size_t)row * D_DIM + t * 8;

    const bf16x8 xv = *(const bf16x8*)(X + base);
    float x[8];
    #pragma unroll
    for (int i = 0; i < 8; ++i) x[i] = (float)xv[i];

    float ss = 0.f;
    #pragma unroll
    for (int i = 0; i < 8; ++i) ss += x[i] * x[i];
    #pragma unroll
    for (int off = 32; off; off >>= 1) ss += __shfl_xor(ss, off);
    __shared__ float red[4];
    if ((t & 63) == 0) red[t >> 6] = ss;
    __syncthreads();
    const float tot = red[0] + red[1] + red[2] + red[3];
    const float rms = rsqrtf(tot * (1.0f / D_DIM) + 1e-6f);

    float wv[8], c[8], sn[8];
    { float4 a = *(const float4*)(w + t * 8); float4 b = *(const float4*)(w + t * 8 + 4);
      wv[0]=a.x; wv[1]=a.y; wv[2]=a.z; wv[3]=a.w; wv[4]=b.x; wv[5]=b.y; wv[6]=b.z; wv[7]=b.w; }
    const size_t cbase = (size_t)row * D_DIM + ((t * 8) & 63);
    { float4 a = *(const float4*)(cosb + cbase); float4 b = *(const float4*)(cosb + cbase + 4);
      c[0]=a.x; c[1]=a.y; c[2]=a.z; c[3]=a.w; c[4]=b.x; c[5]=b.y; c[6]=b.z; c[7]=b.w; }
    { float4 a = *(const float4*)(sinb + cbase); float4 b = *(const float4*)(sinb + cbase + 4);
      sn[0]=a.x; sn[1]=a.y; sn[2]=a.z; sn[3]=a.w; sn[4]=b.x; sn[5]=b.y; sn[6]=b.z; sn[7]=b.w; }

    bf16x8 o;
    #pragma unroll
    for (int p = 0; p < 4; ++p) {
        const float e  = x[2*p]     * rms * wv[2*p];
        const float od = x[2*p + 1] * rms * wv[2*p + 1];
        o[2*p]     = (bf16_t)(e * c[2*p]     - od * sn[2*p]);
        o[2*p + 1] = (bf16_t)(od * c[2*p + 1] + e * sn[2*p + 1]);
    }
    *(bf16x8*)(X + base) = o;
}

// ---------------- MFMA flash attention: 2-wave blocks, 4 blocks/CU ----------------
// q-tile 64 (2 waves x 32q), KV chunks 64. Ks/Vs double-buffered, V-frags ping-pong
// in registers, Ps XOR-swizzled [2][32][64]. LDS = 40960 B exactly -> 4 blocks/CU.
__global__ __launch_bounds__(128, 2) void k_flash(
    const bf16_t* __restrict__ Qb, const bf16_t* __restrict__ Kb,
    const bf16_t* __restrict__ Vt, bf16_t* __restrict__ Ob)
{
    // XCD-aware: each XCD (bid&7) handles 4 heads -> 2 MB KV fits its L2
    const int bid = blockIdx.x;
    const int h    = ((bid & 7) << 2) | (bid >> 8);
    const int qblk = (bid >> 3) & 31;
    const int hc = h * DH;
    const int t = threadIdx.x;
    const int wave = t >> 6, lane = t & 63;
    const int ln = lane & 31, hf = lane >> 5;
    const int qw = qblk * 64 + wave * 32;

    __shared__ bf16_t Ks[2][64][64];   // [key][dh], 16B-granule XOR swizzle
    __shared__ bf16_t Vs[2][64][64];   // [d][key],  same swizzle
    __shared__ bf16_t Ps[2][32][64];   // per-wave [q][key], swizzled; Lw aliased at end

    bf16x8 bq[4];
    #pragma unroll
    for (int kt = 0; kt < 4; ++kt)
        bq[kt] = *(const bf16x8*)(Qb + (size_t)(qw + ln) * D_DIM + hc + kt * 16 + hf * 8);

    // staging: each wave covers 32 rows of K and V (4 gll16 each, 8 rows/instr)
    const int rr = wave * 32 + (lane >> 3);
    const int gc = (lane & 7) ^ (lane >> 3);
    const bf16_t* kg = Kb + (size_t)rr * D_DIM + hc + gc * 8;
    const bf16_t* vg = Vt + (size_t)(hc + rr) * S_LEN + gc * 8;

    auto stageKV = [&](int buf, int kc) {
        #pragma unroll
        for (int i = 0; i < 4; ++i) {
            gll16(kg + (size_t)(kc + 8 * i) * D_DIM, &Ks[buf][wave * 32 + 8 * i][0]);
            gll16(vg + (size_t)(8 * i) * S_LEN + kc, &Vs[buf][wave * 32 + 8 * i][0]);
        }
    };

    floatx16 o0, o1, st;
    #pragma unroll
    for (int r = 0; r < 16; ++r) { o0[r] = 0.f; o1[r] = 0.f; }
    float lsum = 0.f;
    bf16x8 vr[2][8];   // V fragments ping-pong (half*4 + kt)

    const int swz = ln & 7;
    const float c_exp = 0.125f * 1.44269504089f;
    const int NCH = S_LEN / 64;

    auto qk = [&]() {
        #pragma unroll
        for (int r = 0; r < 16; ++r) st[r] = 0.f;
        // reuse st as two 32x32 halves? need both halves: use st for half0, st2 for half1
    };
    (void)qk;

    floatx16 st1;   // second key-half scores

    stageKV(0, 0);

    for (int c = 0; c < NCH; ++c) {
        const int cur = c & 1;
        BAR();                                  // all waves done with buf cur^1 (K read, V in regs)
        if (c + 1 < NCH) {
            stageKV(cur ^ 1, (c + 1) * 64);
            WAIT(8);                            // set c landed; set c+1 in flight
        } else {
            WAIT(0);
        }
        BAR();                                  // everyone's set-c visible

        // exp(c-1) -> Ps (before st is overwritten)
        if (c > 0) {
            #pragma unroll
            for (int g = 0; g < 4; ++g) {
                bf16x4 p0, p1;
                #pragma unroll
                for (int r4 = 0; r4 < 4; ++r4) {
                    const float e0 = __builtin_amdgcn_exp2f(st[4 * g + r4] * c_exp);
                    const float e1 = __builtin_amdgcn_exp2f(st1[4 * g + r4] * c_exp);
                    p0[r4] = (bf16_t)e0; p1[r4] = (bf16_t)e1;
                    lsum += e0 + e1;
                }
                *(bf16x4*)&Ps[wave][ln][((0 + g) ^ swz) * 8 + 4 * hf] = p0;
                *(bf16x4*)&Ps[wave][ln][((4 + g) ^ swz) * 8 + 4 * hf] = p1;
            }
        }

        // S^T = K . Q^T  (chunk c)
        #pragma unroll
        for (int r = 0; r < 16; ++r) { st[r] = 0.f; st1[r] = 0.f; }
        #pragma unroll
        for (int kt = 0; kt < 4; ++kt) {
            const int ch = 2 * kt + hf;
            const bf16x8 a0 = *(const bf16x8*)&Ks[cur][ln]     [(ch ^ swz) * 8];
            const bf16x8 a1 = *(const bf16x8*)&Ks[cur][32 + ln][(ch ^ swz) * 8];
            st  = __builtin_amdgcn_mfma_f32_32x32x16_bf16(a0, bq[kt], st,  0, 0, 0);
            st1 = __builtin_amdgcn_mfma_f32_32x32x16_bf16(a1, bq[kt], st1, 0, 0, 0);
        }

        // V(c) -> registers (used next iter)
        #pragma unroll
        for (int kt = 0; kt < 4; ++kt) {
            const int ch = 2 * kt + hf;
            vr[cur][kt]     = *(const bf16x8*)&Vs[cur][ln]     [(ch ^ swz) * 8];
            vr[cur][4 + kt] = *(const bf16x8*)&Vs[cur][32 + ln][(ch ^ swz) * 8];
        }

        // O += P(c-1) V(c-1)
        if (c > 0) {
            DSWAIT();   // P writes + V reg loads retired (in-order DS pipe)
            #pragma unroll
            for (int kt = 0; kt < 4; ++kt) {
                const bf16x8 ap = *(const bf16x8*)&Ps[wave][ln][((2 * kt + hf) ^ swz) * 8];
                o0 = __builtin_amdgcn_mfma_f32_32x32x16_bf16(ap, vr[cur ^ 1][kt],     o0, 0, 0, 0);
                o1 = __builtin_amdgcn_mfma_f32_32x32x16_bf16(ap, vr[cur ^ 1][4 + kt], o1, 0, 0, 0);
            }
        }
        DSWAIT();       // all own DS ops retired before next barrier
    }

    // drain: exp + PV of chunk NCH-1
    #pragma unroll
    for (int g = 0; g < 4; ++g) {
        bf16x4 p0, p1;
        #pragma unroll
        for (int r4 = 0; r4 < 4; ++r4) {
            const float e0 = __builtin_amdgcn_exp2f(st[4 * g + r4] * c_exp);
            const float e1 = __builtin_amdgcn_exp2f(st1[4 * g + r4] * c_exp);
            p0[r4] = (bf16_t)e0; p1[r4] = (bf16_t)e1;
            lsum += e0 + e1;
        }
        *(bf16x4*)&Ps[wave][ln][((0 + g) ^ swz) * 8 + 4 * hf] = p0;
        *(bf16x4*)&Ps[wave][ln][((4 + g) ^ swz) * 8 + 4 * hf] = p1;
    }
    DSWAIT();
    {
        const int last = (NCH - 1) & 1;
        #pragma unroll
        for (int kt = 0; kt < 4; ++kt) {
            const bf16x8 ap = *(const bf16x8*)&Ps[wave][ln][((2 * kt + hf) ^ swz) * 8];
            o0 = __builtin_amdgcn_mfma_f32_32x32x16_bf16(ap, vr[last][kt],     o0, 0, 0, 0);
            o1 = __builtin_amdgcn_mfma_f32_32x32x16_bf16(ap, vr[last][4 + kt], o1, 0, 0, 0);
        }
    }

    // l redistribution via LDS (aliases dead Ps[wave] region)
    float* Lwp = (float*)&Ps[wave][0][0];
    const float ltot = lsum + __shfl_xor(lsum, 32);
    if (hf == 0) Lwp[ln] = ltot;
    DSWAIT();
    float4 li[4];
    li[0] = *(const float4*)&Lwp[4 * hf];
    li[1] = *(const float4*)&Lwp[8 + 4 * hf];
    li[2] = *(const float4*)&Lwp[16 + 4 * hf];
    li[3] = *(const float4*)&Lwp[24 + 4 * hf];

    #pragma unroll
    for (int r = 0; r < 16; ++r) {
        const int row = (r & 3) + 8 * (r >> 2) + 4 * hf;
        const float lv = (r & 3) == 0 ? li[r >> 2].x : (r & 3) == 1 ? li[r >> 2].y
                       : (r & 3) == 2 ? li[r >> 2].z : li[r >> 2].w;
        const float inv = 1.0f / lv;
        Ob[(size_t)(qw + row) * D_DIM + hc + ln]      = (bf16_t)(o0[r] * inv);
        Ob[(size_t)(qw + row) * D_DIM + hc + 32 + ln] = (bf16_t)(o1[r] * inv);
    }
}

// ---------------- launcher ----------------
extern "C" void kernel_launch(void* const* d_in, const int* in_sizes, int n_in,
                              void* d_out, int out_size, void* d_ws, size_t ws_size,
                              hipStream_t stream) {
    const float* hs   = (const float*)d_in[0];
    const float* cosb = (const float*)d_in[1];
    const float* sinb = (const float*)d_in[2];
    const float* Wq   = (const float*)d_in[3];
    const float* bq   = (const float*)d_in[4];
    const float* Wk   = (const float*)d_in[5];
    const float* bk   = (const float*)d_in[6];
    const float* Wv   = (const float*)d_in[7];
    const float* bv   = (const float*)d_in[8];
    const float* qw   = (const float*)d_in[9];
    const float* kw   = (const float*)d_in[10];
    const float* Wo   = (const float*)d_in[11];
    const float* bo   = (const float*)d_in[12];
    float* out = (float*)d_out;

    char* ws = (char*)d_ws;
    bf16_t* Xb  = (bf16_t*)(ws);
    bf16_t* Wqt = (bf16_t*)(ws + ((size_t)8  << 20));
    bf16_t* Wkt = (bf16_t*)(ws + ((size_t)16 << 20));
    bf16_t* Wvt = (bf16_t*)(ws + ((size_t)24 << 20));
    bf16_t* Wot = (bf16_t*)(ws + ((size_t)32 << 20));
    bf16_t* Qb  = (bf16_t*)(ws + ((size_t)40 << 20));
    bf16_t* Kb  = (bf16_t*)(ws + ((size_t)48 << 20));
    bf16_t* Vt  = (bf16_t*)(ws + ((size_t)56 << 20));
    bf16_t* Ob  = (bf16_t*)(ws + ((size_t)64 << 20));
    float*  P0  = (float*) (ws);                       // aliases Xb/Wqt (dead)
    float*  P1  = (float*) (ws + ((size_t)16 << 20));  // aliases Wkt/Wvt (dead)
    float*  P2  = (float*) (ws + ((size_t)48 << 20));  // aliases Kb/Vt (dead)

    const int n = S_LEN * D_DIM;

    // fused cvt + 4x weight transpose
    k_prep<<<dim3(32, 32, 5), 256, 0, stream>>>(hs, Xb, Wq, Wk, Wv, Wo, Wqt, Wkt, Wvt, Wot);

    // QKV projection: Q,K bf16 row-major; V -> bf16 per-head transposed Vt
    k_gemm_qkv<<<dim3(D_DIM / BN, S_LEN / BM, 3), 256, 0, stream>>>(
        Xb, Wqt, Wkt, Wvt, bq, bk, bv, Qb, Kb, Vt, S_LEN, D_DIM, D_DIM);

    // RMSNorm + RoPE, bf16 in-place
    k_norm_rope<<<dim3(S_LEN, 1, 2), 256, 0, stream>>>(Qb, Kb, qw, kw, cosb, sinb);

    // MFMA flash attention -> bf16 activations (1024 blocks x 128 threads)
    k_flash<<<1024, 128, 0, stream>>>(Qb, Kb, Vt, Ob);

    // output projection: split-K=3 partials + reduce(+bias)
    k_gemm_splitk<<<dim3(D_DIM / BN, S_LEN / BM, 3), 256, 0, stream>>>(
        Ob, Wot, P0, P1, P2, S_LEN, D_DIM, D_DIM);
    k_reduce_bias<<<n / (256 * 4), 256, 0, stream>>>(P0, P1, P2, bo, out);
}